// Round 1
// baseline (263.274 us; speedup 1.0000x reference)
//
#include <hip/hip_runtime.h>

typedef __attribute__((ext_vector_type(8))) short s16x8;
typedef __attribute__((ext_vector_type(4))) short s16x4;
typedef __attribute__((ext_vector_type(4))) float f32x4;

#define BB   512
#define LL   2048
#define DD   128
#define HH   128
#define SUB  128   // leaves per block in kernel 1
#define NSUB (LL / SUB)  // 16 subtree roots per sample

// f32 -> bf16 bits, round-to-nearest-even (inputs finite)
__device__ __forceinline__ short f2bf(float x) {
  unsigned u = __builtin_bit_cast(unsigned, x);
  u += 0x7fffu + ((u >> 16) & 1u);
  return (short)(u >> 16);
}
__device__ __forceinline__ float bf2f(short s) {
  return __builtin_bit_cast(float, ((unsigned)(unsigned short)s) << 16);
}
// tanh(x) = (e^2x - 1)/(e^2x + 1); clamp so e^2x stays finite
__device__ __forceinline__ float tanh_fast(float x) {
  float cx = fminf(10.f, fmaxf(-10.f, x));
  float e2 = __expf(2.f * cx);
  return (e2 - 1.f) * __builtin_amdgcn_rcpf(e2 + 1.f);
}

// LDS byte address for [row][inner] in a [128][256B] bf16 tile.
// Swizzle chosen for stride-2-row ds_read_b128 (tree levels): without it,
// 256B row stride puts all 16 quarter-wave lanes on the same bank quad.
__device__ __forceinline__ int swz(int row, int inner) {
  return row * 256 + (inner ^ (((row >> 1) & 7) << 4));
}

__global__ __launch_bounds__(256, 2) void k_subtree(
    const int* __restrict__ ids, const float* __restrict__ emb,
    const float* __restrict__ Win, const float* __restrict__ bin,
    const float* __restrict__ Wcomp, const float* __restrict__ bcomp,
    float* __restrict__ ws) {
  __shared__ __align__(16) short ldsA[SUB * 128];  // 32 KB
  __shared__ __align__(16) short ldsB[SUB * 128];  // 32 KB
  const int blk = blockIdx.x;           // = b*16 + s ; leaves [blk*128, +128)
  const int tid = threadIdx.x;
  const int wave = tid >> 6, lane = tid & 63;
  const int lh = lane >> 4;             // k-group 0..3
  const int lm = lane & 15;             // A-row / B-col / D-col within tile
  const int n0 = wave * 32;             // this wave owns output cols [n0, n0+32)

  // ---- 1) prefetch leaf ids early (covers latency under weight loads) ----
  int idv[16];
  const long idbase = (long)blk * SUB;
#pragma unroll
  for (int it = 0; it < 16; ++it)
    idv[it] = ids[idbase + it * 8 + wave * 2 + (lane >> 5)];

  // ---- 2) weight B-fragments in registers (bf16) ----
  // B-frag layout: elem j = W[kt*32 + lh*8 + j][n0 + nt*16 + lm]
  // (same k-mapping as A-frags -> any HW k-permutation cancels)
  s16x8 wfin[4][2];
#pragma unroll
  for (int kt = 0; kt < 4; ++kt)
#pragma unroll
    for (int nt = 0; nt < 2; ++nt) {
      s16x8 f;
#pragma unroll
      for (int j = 0; j < 8; ++j)
        f[j] = f2bf(Win[(kt * 32 + lh * 8 + j) * HH + n0 + nt * 16 + lm]);
      wfin[kt][nt] = f;
    }
  s16x8 wfc[8][2];
#pragma unroll
  for (int kt = 0; kt < 8; ++kt)
#pragma unroll
    for (int nt = 0; nt < 2; ++nt) {
      s16x8 f;
#pragma unroll
      for (int j = 0; j < 8; ++j)
        f[j] = f2bf(Wcomp[(kt * 32 + lh * 8 + j) * HH + n0 + nt * 16 + lm]);
      wfc[kt][nt] = f;
    }
  const float bi0 = bin[n0 + lm], bi1 = bin[n0 + 16 + lm];
  const float bc0 = bcomp[n0 + lm], bc1 = bcomp[n0 + 16 + lm];

  // ---- 3) gather embeddings -> ldsA as bf16 (swizzled) ----
  // half-wave per row: 32 lanes x float4 = 128 floats = one row
#pragma unroll
  for (int it = 0; it < 16; ++it) {
    int r = it * 8 + wave * 2 + (lane >> 5);
    const float4 v = ((const float4*)(emb + (long)idv[it] * DD))[lane & 31];
    s16x4 sv;
    sv[0] = f2bf(v.x); sv[1] = f2bf(v.y); sv[2] = f2bf(v.z); sv[3] = f2bf(v.w);
    *(s16x4*)((char*)ldsA + swz(r, (lane & 31) * 8)) = sv;
  }
  __syncthreads();

  // ---- 4) h0 = E @ W_in + b_in -> ldsB (NO tanh at level 0) ----
#pragma unroll 1
  for (int mt = 0; mt < 8; ++mt) {
    s16x8 a[4];
#pragma unroll
    for (int kt = 0; kt < 4; ++kt)
      a[kt] = *(const s16x8*)((char*)ldsA + swz(mt * 16 + lm, kt * 64 + lh * 16));
    f32x4 c0 = {0.f, 0.f, 0.f, 0.f}, c1 = {0.f, 0.f, 0.f, 0.f};
#pragma unroll
    for (int kt = 0; kt < 4; ++kt) {
      c0 = __builtin_amdgcn_mfma_f32_16x16x32_bf16(a[kt], wfin[kt][0], c0, 0, 0, 0);
      c1 = __builtin_amdgcn_mfma_f32_16x16x32_bf16(a[kt], wfin[kt][1], c1, 0, 0, 0);
    }
#pragma unroll
    for (int r = 0; r < 4; ++r) {
      int row = mt * 16 + lh * 4 + r;  // D: row=(lane>>4)*4+reg, col=lane&15
      *(short*)((char*)ldsB + swz(row, (n0 + lm) * 2)) = f2bf(c0[r] + bi0);
      *(short*)((char*)ldsB + swz(row, (n0 + 16 + lm) * 2)) = f2bf(c1[r] + bi1);
    }
  }
  __syncthreads();

  // ---- 5) seven tree levels in LDS (ping-pong) ----
  short* src = ldsB;
  short* dst = ldsA;
  int Rout = 64;
#pragma unroll 1
  for (int lev = 0; lev < 7; ++lev) {
    int mtiles = (Rout >= 16) ? (Rout >> 4) : 1;  // pad M to 16 at deep levels
#pragma unroll 1
    for (int mt = 0; mt < mtiles; ++mt) {
      s16x8 a[8];
#pragma unroll
      for (int kt = 0; kt < 8; ++kt) {
        int k = kt * 32 + lh * 8;                 // k in [0,256): pair-concat
        int rowbuf = 2 * (mt * 16 + lm) + (k >> 7);
        a[kt] = *(const s16x8*)((char*)src + swz(rowbuf, (k & 127) * 2));
      }
      f32x4 c0 = {0.f, 0.f, 0.f, 0.f}, c1 = {0.f, 0.f, 0.f, 0.f};
#pragma unroll
      for (int kt = 0; kt < 8; ++kt) {
        c0 = __builtin_amdgcn_mfma_f32_16x16x32_bf16(a[kt], wfc[kt][0], c0, 0, 0, 0);
        c1 = __builtin_amdgcn_mfma_f32_16x16x32_bf16(a[kt], wfc[kt][1], c1, 0, 0, 0);
      }
      if (lev == 6) {
        // Rout == 1: only D-row 0 (lh==0, reg 0) is valid; write f32 root to ws
        if (lh == 0) {
          ws[(long)blk * HH + n0 + lm]      = tanh_fast(c0[0] + bc0);
          ws[(long)blk * HH + n0 + 16 + lm] = tanh_fast(c1[0] + bc1);
        }
      } else {
#pragma unroll
        for (int r = 0; r < 4; ++r) {
          int row = mt * 16 + lh * 4 + r;
          if (row < Rout) {
            *(short*)((char*)dst + swz(row, (n0 + lm) * 2)) =
                f2bf(tanh_fast(c0[r] + bc0));
            *(short*)((char*)dst + swz(row, (n0 + 16 + lm) * 2)) =
                f2bf(tanh_fast(c1[r] + bc1));
          }
        }
      }
    }
    __syncthreads();
    short* t = src; src = dst; dst = t;
    Rout >>= 1;
  }
}

// ---- kernel 2: per-sample 16 -> 1 + classifier (fp32 VALU, W_comp bf16 in LDS)
template <int ROUT>
__device__ __forceinline__ void level_step(const float* src, float* dst,
                                           const short* wlds, int n, int ig,
                                           float bc) {
  constexpr int NI = (ROUT >= 2) ? (ROUT / 2) : 1;
  float accs[NI];
#pragma unroll
  for (int ii = 0; ii < NI; ++ii) accs[ii] = 0.f;
  const bool active = (ROUT >= 2) || (ig == 0);
  if (active) {
#pragma unroll 4
    for (int k = 0; k < 256; ++k) {
      float w = bf2f(wlds[k * 128 + n]);
#pragma unroll
      for (int ii = 0; ii < NI; ++ii)
        accs[ii] += src[(ig + 2 * ii) * 256 + k] * w;  // src row bcast, w coalesced
    }
#pragma unroll
    for (int ii = 0; ii < NI; ++ii)
      dst[(ig + 2 * ii) * 128 + n] = tanh_fast(accs[ii] + bc);
  }
  __syncthreads();
}

__global__ __launch_bounds__(256, 2) void k_root(
    const float* __restrict__ ws, const float* __restrict__ Wcomp,
    const float* __restrict__ bcomp, const float* __restrict__ Wcls,
    const float* __restrict__ bcls, float* __restrict__ out) {
  __shared__ short wlds[256 * 128];  // bf16 W_comp, 64 KB
  __shared__ float h0[16 * 128];
  __shared__ float h1[8 * 128];
  const int b = blockIdx.x, tid = threadIdx.x;
  for (int i = tid; i < 256 * 128; i += 256) wlds[i] = f2bf(Wcomp[i]);
  for (int i = tid; i < 16 * 128; i += 256) h0[i] = ws[(long)b * (NSUB * HH) + i];
  __syncthreads();
  const int n = tid & 127, ig = tid >> 7;
  const float bc = bcomp[n];
  level_step<8>(h0, h1, wlds, n, ig, bc);
  level_step<4>(h1, h0, wlds, n, ig, bc);
  level_step<2>(h0, h1, wlds, n, ig, bc);
  level_step<1>(h1, h0, wlds, n, ig, bc);
  // root now in h0[0..127]
  if (tid < 2) {
    float acc = bcls[tid];
    for (int k = 0; k < 128; ++k) acc += h0[k] * Wcls[k * 2 + tid];
    out[b * 2 + tid] = acc;
  }
}

extern "C" void kernel_launch(void* const* d_in, const int* in_sizes, int n_in,
                              void* d_out, int out_size, void* d_ws, size_t ws_size,
                              hipStream_t stream) {
  const int*   ids   = (const int*)d_in[0];
  const float* emb   = (const float*)d_in[1];
  const float* Win   = (const float*)d_in[2];
  const float* bin   = (const float*)d_in[3];
  const float* Wcomp = (const float*)d_in[4];
  const float* bcomp = (const float*)d_in[5];
  const float* Wcls  = (const float*)d_in[6];
  const float* bcls  = (const float*)d_in[7];
  float* ws  = (float*)d_ws;   // 512*16*128 f32 = 4 MB subtree roots
  float* out = (float*)d_out;

  hipLaunchKernelGGL(k_subtree, dim3(BB * NSUB), dim3(256), 0, stream,
                     ids, emb, Win, bin, Wcomp, bcomp, ws);
  hipLaunchKernelGGL(k_root, dim3(BB), dim3(256), 0, stream,
                     ws, Wcomp, bcomp, Wcls, bcls, out);
}

// Round 2
// 232.857 us; speedup vs baseline: 1.1306x; 1.1306x over previous
//
#include <hip/hip_runtime.h>

typedef __attribute__((ext_vector_type(8))) short s16x8;
typedef __attribute__((ext_vector_type(4))) short s16x4;
typedef __attribute__((ext_vector_type(4))) float f32x4;

#define BB   512
#define LL   2048
#define DD   128
#define HH   128
#define SUB  128   // leaves per block in kernel 1
#define NSUB (LL / SUB)  // 16 subtree roots per sample

// f32 -> bf16 bits, round-to-nearest-even (inputs finite)
__device__ __forceinline__ short f2bf(float x) {
  unsigned u = __builtin_bit_cast(unsigned, x);
  u += 0x7fffu + ((u >> 16) & 1u);
  return (short)(u >> 16);
}
__device__ __forceinline__ float bf2f(short s) {
  return __builtin_bit_cast(float, ((unsigned)(unsigned short)s) << 16);
}
// packed f32x2 -> bf16x2 in one VALU op (gfx950 v_cvt_pk_bf16_f32, RNE)
__device__ __forceinline__ unsigned pk_bf16(float a, float b) {
  unsigned r;
  asm("v_cvt_pk_bf16_f32 %0, %1, %2" : "=v"(r) : "v"(a), "v"(b));
  return r;
}
// tanh(x) = (e^2x - 1)/(e^2x + 1); clamp so e^2x stays finite
__device__ __forceinline__ float tanh_fast(float x) {
  float cx = fminf(10.f, fmaxf(-10.f, x));
  float e2 = __expf(2.f * cx);
  return (e2 - 1.f) * __builtin_amdgcn_rcpf(e2 + 1.f);
}

// LDS byte address for [row][inner] in a [128][256B] bf16 tile.
// Swizzle for stride-row ds_read_b128: 256B row stride would put all
// quarter-wave lanes on the same bank quad (16-way conflict) without it.
__device__ __forceinline__ int swz(int row, int inner) {
  return row * 256 + (inner ^ (((row >> 1) & 7) << 4));
}

// ---- prep: W_in^T, W_comp^T as bf16 (fragment loads become contiguous) ----
__global__ __launch_bounds__(256) void k_prep(
    const float* __restrict__ Win, const float* __restrict__ Wcomp,
    short* __restrict__ WiT, short* __restrict__ WcT) {
  const int i0 = blockIdx.x * 256 + threadIdx.x;
  const int stride = gridDim.x * 256;
  for (int idx = i0; idx < 128 * 128; idx += stride) {
    int n = idx >> 7, k = idx & 127;
    WiT[idx] = f2bf(Win[k * 128 + n]);     // WiT[n][k]
  }
  for (int idx = i0; idx < 128 * 256; idx += stride) {
    int n = idx >> 8, k = idx & 255;
    WcT[idx] = f2bf(Wcomp[k * 128 + n]);   // WcT[n][k]
  }
}

__global__ __launch_bounds__(256, 2) void k_subtree(
    const int* __restrict__ ids, const float* __restrict__ emb,
    const short* __restrict__ WiT, const float* __restrict__ bin,
    const short* __restrict__ WcT, const float* __restrict__ bcomp,
    float* __restrict__ ws) {
  __shared__ __align__(16) short ldsA[SUB * 128];  // 32 KB
  __shared__ __align__(16) short ldsB[SUB * 128];  // 32 KB
  const int blk = blockIdx.x;           // = b*16 + s ; leaves [blk*128, +128)
  const int tid = threadIdx.x;
  const int wave = tid >> 6, lane = tid & 63;
  const int lh = lane >> 4;             // k-group 0..3
  const int lm = lane & 15;             // A-row / B-col / D-col within tile
  const int n0 = wave * 32;             // this wave owns output cols [n0, n0+32)
  const int col0 = n0 + 2 * lm;         // interleaved: lane owns cols col0, col0+1

  // ---- 1) prefetch leaf ids early ----
  int idv[16];
  const long idbase = (long)blk * SUB;
#pragma unroll
  for (int it = 0; it < 16; ++it)
    idv[it] = ids[idbase + it * 8 + wave * 2 + (lane >> 5)];

  // ---- 2) weight B-fragments: direct s16x8 loads from pre-transposed bf16 ----
  // frag elem j = W[kt*32 + lh*8 + j][col0 + nt]  (same k-map as A-frags)
  s16x8 wfin[4][2];
#pragma unroll
  for (int kt = 0; kt < 4; ++kt)
#pragma unroll
    for (int nt = 0; nt < 2; ++nt)
      wfin[kt][nt] = *(const s16x8*)(WiT + (col0 + nt) * 128 + kt * 32 + lh * 8);
  s16x8 wfc[8][2];
#pragma unroll
  for (int kt = 0; kt < 8; ++kt)
#pragma unroll
    for (int nt = 0; nt < 2; ++nt)
      wfc[kt][nt] = *(const s16x8*)(WcT + (col0 + nt) * 256 + kt * 32 + lh * 8);
  const float2 biv = *(const float2*)(bin + col0);
  const float2 bcv = *(const float2*)(bcomp + col0);
  const float bi0 = biv.x, bi1 = biv.y;
  const float bc0 = bcv.x, bc1 = bcv.y;

  // ---- 3) gather embeddings -> ldsA as bf16 (swizzled, packed) ----
#pragma unroll
  for (int it = 0; it < 16; ++it) {
    int r = it * 8 + wave * 2 + (lane >> 5);
    const float4 v = ((const float4*)(emb + (long)idv[it] * DD))[lane & 31];
    uint2 pv;
    pv.x = pk_bf16(v.x, v.y);
    pv.y = pk_bf16(v.z, v.w);
    *(uint2*)((char*)ldsA + swz(r, (lane & 31) * 8)) = pv;
  }
  __syncthreads();

  // ---- 4) h0 = E @ W_in + b_in -> ldsB (NO tanh at level 0) ----
#pragma unroll 1
  for (int mt = 0; mt < 8; ++mt) {
    s16x8 a[4];
#pragma unroll
    for (int kt = 0; kt < 4; ++kt)
      a[kt] = *(const s16x8*)((char*)ldsA + swz(mt * 16 + lm, kt * 64 + lh * 16));
    f32x4 c0 = {0.f, 0.f, 0.f, 0.f}, c1 = {0.f, 0.f, 0.f, 0.f};
#pragma unroll
    for (int kt = 0; kt < 4; ++kt) {
      c0 = __builtin_amdgcn_mfma_f32_16x16x32_bf16(a[kt], wfin[kt][0], c0, 0, 0, 0);
      c1 = __builtin_amdgcn_mfma_f32_16x16x32_bf16(a[kt], wfin[kt][1], c1, 0, 0, 0);
    }
#pragma unroll
    for (int r = 0; r < 4; ++r) {
      int row = mt * 16 + lh * 4 + r;  // D: row=(lane>>4)*4+reg, col per B-map
      *(unsigned*)((char*)ldsB + swz(row, col0 * 2)) =
          pk_bf16(c0[r] + bi0, c1[r] + bi1);
    }
  }
  __syncthreads();

  // ---- 5) seven tree levels in LDS (ping-pong) ----
  short* src = ldsB;
  short* dst = ldsA;
  int Rout = 64;
#pragma unroll 1
  for (int lev = 0; lev < 7; ++lev) {
    int mtiles = (Rout >= 16) ? (Rout >> 4) : 1;  // pad M to 16 at deep levels
#pragma unroll 1
    for (int mt = 0; mt < mtiles; ++mt) {
      s16x8 a[8];
#pragma unroll
      for (int kt = 0; kt < 8; ++kt) {
        int k = kt * 32 + lh * 8;                 // k in [0,256): pair-concat
        int rowbuf = 2 * (mt * 16 + lm) + (k >> 7);
        a[kt] = *(const s16x8*)((char*)src + swz(rowbuf, (k & 127) * 2));
      }
      f32x4 c0 = {0.f, 0.f, 0.f, 0.f}, c1 = {0.f, 0.f, 0.f, 0.f};
#pragma unroll
      for (int kt = 0; kt < 8; ++kt) {
        c0 = __builtin_amdgcn_mfma_f32_16x16x32_bf16(a[kt], wfc[kt][0], c0, 0, 0, 0);
        c1 = __builtin_amdgcn_mfma_f32_16x16x32_bf16(a[kt], wfc[kt][1], c1, 0, 0, 0);
      }
      if (lev == 6) {
        // Rout == 1: only D-row 0 (lh==0, reg 0) is valid; f32x2 root to ws
        if (lh == 0) {
          float2 rv;
          rv.x = tanh_fast(c0[0] + bc0);
          rv.y = tanh_fast(c1[0] + bc1);
          *(float2*)(ws + (long)blk * HH + col0) = rv;
        }
      } else {
#pragma unroll
        for (int r = 0; r < 4; ++r) {
          int row = mt * 16 + lh * 4 + r;
          if (row < Rout) {
            *(unsigned*)((char*)dst + swz(row, col0 * 2)) =
                pk_bf16(tanh_fast(c0[r] + bc0), tanh_fast(c1[r] + bc1));
          }
        }
      }
    }
    __syncthreads();
    short* t = src; src = dst; dst = t;
    Rout >>= 1;
  }
}

// ---- kernel 2: per-sample 16 -> 1 + classifier (fp32 VALU, W_comp bf16 in LDS)
template <int ROUT>
__device__ __forceinline__ void level_step(const float* src, float* dst,
                                           const short* wlds, int n, int ig,
                                           float bc) {
  constexpr int NI = (ROUT >= 2) ? (ROUT / 2) : 1;
  float accs[NI];
#pragma unroll
  for (int ii = 0; ii < NI; ++ii) accs[ii] = 0.f;
  const bool active = (ROUT >= 2) || (ig == 0);
  if (active) {
#pragma unroll 4
    for (int k = 0; k < 256; ++k) {
      float w = bf2f(wlds[k * 128 + n]);
#pragma unroll
      for (int ii = 0; ii < NI; ++ii)
        accs[ii] += src[(ig + 2 * ii) * 256 + k] * w;  // src row bcast, w coalesced
    }
#pragma unroll
    for (int ii = 0; ii < NI; ++ii)
      dst[(ig + 2 * ii) * 128 + n] = tanh_fast(accs[ii] + bc);
  }
  __syncthreads();
}

__global__ __launch_bounds__(256, 2) void k_root(
    const float* __restrict__ ws, const float* __restrict__ Wcomp,
    const float* __restrict__ bcomp, const float* __restrict__ Wcls,
    const float* __restrict__ bcls, float* __restrict__ out) {
  __shared__ short wlds[256 * 128];  // bf16 W_comp, 64 KB
  __shared__ float h0[16 * 128];
  __shared__ float h1[8 * 128];
  const int b = blockIdx.x, tid = threadIdx.x;
  for (int i = tid; i < 256 * 128; i += 256) wlds[i] = f2bf(Wcomp[i]);
  for (int i = tid; i < 16 * 128; i += 256) h0[i] = ws[(long)b * (NSUB * HH) + i];
  __syncthreads();
  const int n = tid & 127, ig = tid >> 7;
  const float bc = bcomp[n];
  level_step<8>(h0, h1, wlds, n, ig, bc);
  level_step<4>(h1, h0, wlds, n, ig, bc);
  level_step<2>(h0, h1, wlds, n, ig, bc);
  level_step<1>(h1, h0, wlds, n, ig, bc);
  // root now in h0[0..127]
  if (tid < 2) {
    float acc = bcls[tid];
    for (int k = 0; k < 128; ++k) acc += h0[k] * Wcls[k * 2 + tid];
    out[b * 2 + tid] = acc;
  }
}

extern "C" void kernel_launch(void* const* d_in, const int* in_sizes, int n_in,
                              void* d_out, int out_size, void* d_ws, size_t ws_size,
                              hipStream_t stream) {
  const int*   ids   = (const int*)d_in[0];
  const float* emb   = (const float*)d_in[1];
  const float* Win   = (const float*)d_in[2];
  const float* bin   = (const float*)d_in[3];
  const float* Wcomp = (const float*)d_in[4];
  const float* bcomp = (const float*)d_in[5];
  const float* Wcls  = (const float*)d_in[6];
  const float* bcls  = (const float*)d_in[7];
  char* wsb = (char*)d_ws;
  float* roots = (float*)wsb;                         // 4 MB subtree roots
  short* WcT   = (short*)(wsb + (4 << 20));           // 64 KB bf16 W_comp^T
  short* WiT   = (short*)(wsb + (4 << 20) + 65536);   // 32 KB bf16 W_in^T
  float* out = (float*)d_out;

  hipLaunchKernelGGL(k_prep, dim3(64), dim3(256), 0, stream, Win, Wcomp, WiT, WcT);
  hipLaunchKernelGGL(k_subtree, dim3(BB * NSUB), dim3(256), 0, stream,
                     ids, emb, WiT, bin, WcT, bcomp, roots);
  hipLaunchKernelGGL(k_root, dim3(BB), dim3(256), 0, stream,
                     roots, Wcomp, bcomp, Wcls, bcls, out);
}

// Round 4
// 161.726 us; speedup vs baseline: 1.6279x; 1.4398x over previous
//
#include <hip/hip_runtime.h>

typedef __attribute__((ext_vector_type(8))) short s16x8;
typedef __attribute__((ext_vector_type(4))) float f32x4;

#define BB   512
#define LL   2048
#define DD   128
#define HH   128
#define SUB  128              // leaves per k1 block
#define NSUB (LL / SUB)       // 16 subtrees per sample
#define K1ROWS 8              // rows k1 leaves per subtree (4 comp levels)
#define K2ROWS (NSUB * K1ROWS)  // 128 rows per sample into k2

// f32 -> bf16 bits, RNE
__device__ __forceinline__ short f2bf(float x) {
  unsigned u = __builtin_bit_cast(unsigned, x);
  u += 0x7fffu + ((u >> 16) & 1u);
  return (short)(u >> 16);
}
// packed f32x2 -> bf16x2 (gfx950 v_cvt_pk_bf16_f32, RNE)
__device__ __forceinline__ unsigned pk_bf16(float a, float b) {
  unsigned r;
  asm("v_cvt_pk_bf16_f32 %0, %1, %2" : "=v"(r) : "v"(a), "v"(b));
  return r;
}
// tanh via exp; valid-row preacts are norm-bounded, garbage rows write-masked
__device__ __forceinline__ float tanh_fast(float x) {
  float e2 = __expf(2.f * x);
  return (e2 - 1.f) * __builtin_amdgcn_rcpf(e2 + 1.f);
}

// LDS byte address for [row][inner(bytes)] in a [*][256B] bf16 tile; XOR
// swizzle breaks the 256B-row-stride bank alignment for strided ds_read_b128.
__device__ __forceinline__ int swz(int row, int inner) {
  return row * 256 + (inner ^ (((row >> 1) & 7) << 4));
}

// ---- prep: W_in^T, W_comp^T as bf16 ----
__global__ __launch_bounds__(256) void k_prep(
    const float* __restrict__ Win, const float* __restrict__ Wcomp,
    short* __restrict__ WiT, short* __restrict__ WcT) {
  const int i0 = blockIdx.x * 256 + threadIdx.x;
  const int stride = gridDim.x * 256;
  for (int idx = i0; idx < 128 * 128; idx += stride) {
    int n = idx >> 7, k = idx & 127;
    WiT[idx] = f2bf(Win[k * 128 + n]);     // WiT[n][k]
  }
  for (int idx = i0; idx < 128 * 256; idx += stride) {
    int n = idx >> 8, k = idx & 255;
    WcT[idx] = f2bf(Wcomp[k * 128 + n]);   // WcT[n][k]
  }
}

// One 16-row tree M-tile: A row i = concat(src[2*(mt_in*16+i)], src[...+1]),
// K=256 against wfc.
__device__ __forceinline__ void tree_mm(const short* src, int mt_in,
                                        const s16x8 (&wfc)[8][2], int lm,
                                        int lh, f32x4& c0, f32x4& c1) {
  s16x8 a[8];
#pragma unroll
  for (int kt = 0; kt < 8; ++kt) {
    int k = kt * 32 + lh * 8;
    int rowbuf = 2 * (mt_in * 16 + lm) + (k >> 7);
    a[kt] = *(const s16x8*)((const char*)src + swz(rowbuf, (k & 127) * 2));
  }
  c0 = (f32x4){0.f, 0.f, 0.f, 0.f};
  c1 = (f32x4){0.f, 0.f, 0.f, 0.f};
#pragma unroll
  for (int kt = 0; kt < 8; ++kt) {
    c0 = __builtin_amdgcn_mfma_f32_16x16x32_bf16(a[kt], wfc[kt][0], c0, 0, 0, 0);
    c1 = __builtin_amdgcn_mfma_f32_16x16x32_bf16(a[kt], wfc[kt][1], c1, 0, 0, 0);
  }
}

__device__ __forceinline__ void h0_tile(const short* ldsE, short* ldsB,
                                        int mtl, int mtg,
                                        const s16x8 (&wfin)[4][2], float bi0,
                                        float bi1, int lm, int lh, int col0) {
  s16x8 a[4];
#pragma unroll
  for (int kt = 0; kt < 4; ++kt)
    a[kt] = *(const s16x8*)((const char*)ldsE +
                            swz(mtl * 16 + lm, kt * 64 + lh * 16));
  f32x4 c0 = {0.f, 0.f, 0.f, 0.f}, c1 = {0.f, 0.f, 0.f, 0.f};
#pragma unroll
  for (int kt = 0; kt < 4; ++kt) {
    c0 = __builtin_amdgcn_mfma_f32_16x16x32_bf16(a[kt], wfin[kt][0], c0, 0, 0, 0);
    c1 = __builtin_amdgcn_mfma_f32_16x16x32_bf16(a[kt], wfin[kt][1], c1, 0, 0, 0);
  }
#pragma unroll
  for (int r = 0; r < 4; ++r) {
    int row = mtg * 16 + lh * 4 + r;
    *(unsigned*)((char*)ldsB + swz(row, col0 * 2)) =
        pk_bf16(c0[r] + bi0, c1[r] + bi1);  // no tanh at level 0
  }
}

__global__ __launch_bounds__(256, 3) void k_subtree(
    const int* __restrict__ ids, const float* __restrict__ emb,
    const short* __restrict__ WiT, const float* __restrict__ bin,
    const short* __restrict__ WcT, const float* __restrict__ bcomp,
    short* __restrict__ wsbf) {
  __shared__ __align__(16) short ldsE[64 * 128];   // 16 KB (E chunk / tree ping)
  __shared__ __align__(16) short ldsB[128 * 128];  // 32 KB
  const int blk = blockIdx.x, tid = threadIdx.x;
  const int wave = tid >> 6, lane = tid & 63;
  const int lh = lane >> 4, lm = lane & 15;
  const int n0 = wave * 32;
  const int col0 = n0 + 2 * lm;  // lane owns cols col0, col0+1

  // leaf ids
  int idv[16];
#pragma unroll
  for (int it = 0; it < 16; ++it)
    idv[it] = ids[(long)blk * SUB + it * 8 + wave * 2 + (lane >> 5)];

  // W_in fragments (live only through h0)
  s16x8 wfin[4][2];
#pragma unroll
  for (int kt = 0; kt < 4; ++kt)
#pragma unroll
    for (int nt = 0; nt < 2; ++nt)
      wfin[kt][nt] = *(const s16x8*)(WiT + (col0 + nt) * 128 + kt * 32 + lh * 8);
  const float2 biv = *(const float2*)(bin + col0);
  const float2 bcv = *(const float2*)(bcomp + col0);

  // gather chunk0 (rows 0-63) -> ldsE
#pragma unroll
  for (int it = 0; it < 8; ++it) {
    int r = it * 8 + wave * 2 + (lane >> 5);
    const float4 v = ((const float4*)(emb + (long)idv[it] * DD))[lane & 31];
    uint2 pv;
    pv.x = pk_bf16(v.x, v.y);
    pv.y = pk_bf16(v.z, v.w);
    *(uint2*)((char*)ldsE + swz(r, (lane & 31) * 8)) = pv;
  }
  // stage chunk1 globals in regs (latency hides under h0 chunk0)
  float4 g1[8];
#pragma unroll
  for (int j = 0; j < 8; ++j)
    g1[j] = ((const float4*)(emb + (long)idv[8 + j] * DD))[lane & 31];
  __syncthreads();

  // h0 chunk0: E rows 0-63 -> ldsB rows 0-63
#pragma unroll 1
  for (int mtl = 0; mtl < 4; ++mtl)
    h0_tile(ldsE, ldsB, mtl, mtl, wfin, biv.x, biv.y, lm, lh, col0);
  __syncthreads();  // all waves done reading ldsE

  // write chunk1 -> ldsE
#pragma unroll
  for (int j = 0; j < 8; ++j) {
    int r = j * 8 + wave * 2 + (lane >> 5);
    uint2 pv;
    pv.x = pk_bf16(g1[j].x, g1[j].y);
    pv.y = pk_bf16(g1[j].z, g1[j].w);
    *(uint2*)((char*)ldsE + swz(r, (lane & 31) * 8)) = pv;
  }
  __syncthreads();

  // h0 chunk1: -> ldsB rows 64-127
#pragma unroll 1
  for (int mtl = 0; mtl < 4; ++mtl)
    h0_tile(ldsE, ldsB, mtl, 4 + mtl, wfin, biv.x, biv.y, lm, lh, col0);

  // W_comp fragments (wfin now dead)
  s16x8 wfc[8][2];
#pragma unroll
  for (int kt = 0; kt < 8; ++kt)
#pragma unroll
    for (int nt = 0; nt < 2; ++nt)
      wfc[kt][nt] = *(const s16x8*)(WcT + (col0 + nt) * 256 + kt * 32 + lh * 8);
  __syncthreads();

  // lev0: ldsB(128 rows) -> ldsE(64 rows)
#pragma unroll 1
  for (int mt = 0; mt < 4; ++mt) {
    f32x4 c0, c1;
    tree_mm(ldsB, mt, wfc, lm, lh, c0, c1);
#pragma unroll
    for (int r = 0; r < 4; ++r) {
      int row = mt * 16 + lh * 4 + r;
      *(unsigned*)((char*)ldsE + swz(row, col0 * 2)) =
          pk_bf16(tanh_fast(c0[r] + bcv.x), tanh_fast(c1[r] + bcv.y));
    }
  }
  __syncthreads();

  // lev1: ldsE(64) -> ldsB(32)
#pragma unroll 1
  for (int mt = 0; mt < 2; ++mt) {
    f32x4 c0, c1;
    tree_mm(ldsE, mt, wfc, lm, lh, c0, c1);
#pragma unroll
    for (int r = 0; r < 4; ++r) {
      int row = mt * 16 + lh * 4 + r;
      *(unsigned*)((char*)ldsB + swz(row, col0 * 2)) =
          pk_bf16(tanh_fast(c0[r] + bcv.x), tanh_fast(c1[r] + bcv.y));
    }
  }
  __syncthreads();

  // lev2: ldsB(32) -> ldsE(16 rows, FULL — these are level-3 rows)
  {
    f32x4 c0, c1;
    tree_mm(ldsB, 0, wfc, lm, lh, c0, c1);
#pragma unroll
    for (int r = 0; r < 4; ++r) {
      int row = lh * 4 + r;
      *(unsigned*)((char*)ldsE + swz(row, col0 * 2)) =
          pk_bf16(tanh_fast(c0[r] + bcv.x), tanh_fast(c1[r] + bcv.y));
    }
  }
  __syncthreads();

  // lev3: ldsE(16 valid rows; 16-31 stale-but-finite) -> global ws, 8 rows
  {
    f32x4 c0, c1;
    tree_mm(ldsE, 0, wfc, lm, lh, c0, c1);
#pragma unroll
    for (int r = 0; r < 4; ++r) {
      int row = lh * 4 + r;
      if (row < K1ROWS)
        *(unsigned*)(wsbf + ((long)blk * K1ROWS + row) * HH + col0) =
            pk_bf16(tanh_fast(c0[r] + bcv.x), tanh_fast(c1[r] + bcv.y));
    }
  }
}

// ---- k2: per-sample 128 rows -> root -> classifier (MFMA) ----
__global__ __launch_bounds__(256, 2) void k_tree2(
    const short* __restrict__ wsbf, const short* __restrict__ WcT,
    const float* __restrict__ bcomp, const float* __restrict__ Wcls,
    const float* __restrict__ bcls, float* __restrict__ out) {
  __shared__ __align__(16) short srcL[128 * 128];  // 32 KB
  __shared__ __align__(16) short dstS[64 * 128];   // 16 KB
  __shared__ float rootL[128];
  const int b = blockIdx.x, tid = threadIdx.x;
  const int wave = tid >> 6, lane = tid & 63;
  const int lh = lane >> 4, lm = lane & 15;
  const int n0 = wave * 32;
  const int col0 = n0 + 2 * lm;

  s16x8 wfc[8][2];
#pragma unroll
  for (int kt = 0; kt < 8; ++kt)
#pragma unroll
    for (int nt = 0; nt < 2; ++nt)
      wfc[kt][nt] = *(const s16x8*)(WcT + (col0 + nt) * 256 + kt * 32 + lh * 8);
  const float2 bcv = *(const float2*)(bcomp + col0);

  // load 128 rows of bf16 (16 B per lane, coalesced) -> srcL swizzled
#pragma unroll
  for (int it = 0; it < 8; ++it) {
    int row = it * 16 + (tid >> 4);
    s16x8 v = *(const s16x8*)(wsbf + ((long)b * K2ROWS + row) * HH + (tid & 15) * 8);
    *(s16x8*)((char*)srcL + swz(row, (tid & 15) * 16)) = v;
  }
  __syncthreads();

  const short* src = srcL;
  short* dst = dstS;
  // levels: 128->64->32->16->8->4->2->1 ; mtiles 4,2,1,1,1,1,1
  const int mtiles[7] = {4, 2, 1, 1, 1, 1, 1};
  const int rlim[7] = {64, 32, 16, 8, 4, 2, 1};
#pragma unroll 1
  for (int lev = 0; lev < 7; ++lev) {
    int nmt = mtiles[lev], rl = rlim[lev];
#pragma unroll 1
    for (int mt = 0; mt < nmt; ++mt) {
      f32x4 c0, c1;
      tree_mm(src, mt, wfc, lm, lh, c0, c1);
      if (lev == 6) {
        if (lh == 0) {
          rootL[col0] = tanh_fast(c0[0] + bcv.x);
          rootL[col0 + 1] = tanh_fast(c1[0] + bcv.y);
        }
      } else {
#pragma unroll
        for (int r = 0; r < 4; ++r) {
          int row = mt * 16 + lh * 4 + r;
          if (row < rl)
            *(unsigned*)((char*)dst + swz(row, col0 * 2)) =
                pk_bf16(tanh_fast(c0[r] + bcv.x), tanh_fast(c1[r] + bcv.y));
        }
      }
    }
    __syncthreads();
    const short* t = src;
    src = dst;
    dst = (short*)t;
  }

  // classifier: wave 0; lane -> (class = lane&1, k-chunk = lane>>1)
  if (wave == 0) {
    int c = lane & 1, kb = lane >> 1;
    float p = 0.f;
#pragma unroll
    for (int j = 0; j < 4; ++j) {
      int k = kb + 32 * j;
      p += rootL[k] * Wcls[k * 2 + c];
    }
#pragma unroll
    for (int m = 2; m <= 32; m <<= 1) p += __shfl_xor(p, m, 64);
    if (lane < 2) out[b * 2 + lane] = p + bcls[lane];
  }
}

extern "C" void kernel_launch(void* const* d_in, const int* in_sizes, int n_in,
                              void* d_out, int out_size, void* d_ws, size_t ws_size,
                              hipStream_t stream) {
  const int*   ids   = (const int*)d_in[0];
  const float* emb   = (const float*)d_in[1];
  const float* Win   = (const float*)d_in[2];
  const float* bin   = (const float*)d_in[3];
  const float* Wcomp = (const float*)d_in[4];
  const float* bcomp = (const float*)d_in[5];
  const float* Wcls  = (const float*)d_in[6];
  const float* bcls  = (const float*)d_in[7];
  char* wsb = (char*)d_ws;
  short* wsbf = (short*)wsb;                            // 16 MB bf16 k1->k2 rows
  const size_t WSBF_BYTES = (size_t)BB * NSUB * K1ROWS * HH * 2;  // 16 MB
  short* WcT = (short*)(wsb + WSBF_BYTES);              // 64 KB
  short* WiT = (short*)(wsb + WSBF_BYTES + 65536);      // 32 KB
  float* out = (float*)d_out;

  hipLaunchKernelGGL(k_prep, dim3(64), dim3(256), 0, stream, Win, Wcomp, WiT, WcT);
  hipLaunchKernelGGL(k_subtree, dim3(BB * NSUB), dim3(256), 0, stream,
                     ids, emb, WiT, bin, WcT, bcomp, wsbf);
  hipLaunchKernelGGL(k_tree2, dim3(BB), dim3(256), 0, stream,
                     wsbf, WcT, bcomp, Wcls, bcls, out);
}